// Round 10
// baseline (99.739 us; speedup 1.0000x reference)
//
#include <hip/hip_runtime.h>

#define IS 256
#define FCOUNT 4096
#define NEARP 0.1f
#define FARP 100.0f
#define TINYF 1e-12f
#define CAP_T 320        // per-16x16-tile LDS list capacity (mean ~60-90; margin proven R2-R9)
#define DET_GLOBAL 1e-5f // |det| below this -> always evaluated (sliver escape unbounded)
#define ZEPS 2e-4f       // early-z slack: zp >= min(z)-5e-5 proven; 4x margin

// Value barrier: pins a value in a VGPR; no transform across it.
__device__ __forceinline__ float frn(float r) { asm("" : "+v"(r)); return r; }
__device__ __forceinline__ float mulrn(float a, float b) { return frn(a * b); }
__device__ __forceinline__ float addrn(float a, float b) { return frn(a + b); }
__device__ __forceinline__ float subrn(float a, float b) { return frn(a - b); }
__device__ __forceinline__ float divrn(float a, float b) { return frn(a / b); }
__device__ __forceinline__ float fmarn(float a, float b, float c) {
    return frn(__builtin_fmaf(a, b, c));
}

// ---------------------------------------------------------------------------
// R10 = R9 (best, 94.65 us) + phase-B latency-chain removal.
// R9 post-mortem: 8 waves/SIMD gained only 1.7 us; VALUBusy stuck ~46% ->
// the ~40 us raster time is a serial per-iteration dependency
// (ds_read s_i -> wait -> branch -> ds_read abc -> wait -> eval) that TLP
// doesn't hide. Fix: (1) drop the qbit branch — evaluating a face whose
// dilated bbox misses this wave's quadrant is PROVABLY a no-op (fp-inside
// region is contained in bbox(+d); pixel outside => ins=false), so outputs
// are bit-identical; (2) software-pipeline the LDS constants one iteration
// ahead in registers, unconditionally, so ds_reads issue before the prior
// eval consumes its data; (3) phase A stores just f and uses a single
// tile-overlap test (same pool membership as the quadmask!=0 test).
// Everything else (512-thr / 8-wave stripes, partial-argmin + lexicographic
// (z, smaller idx) merge, frn-pinned accept chains, saved-state shade) is
// the R9-verified structure op-for-op.
// LDS: 16,644 (pool) + 8,192 (stripe-1 partials) ~= 24.8 KB -> 4 blocks/CU.
// ---------------------------------------------------------------------------
__global__ __launch_bounds__(512, 8) void fused_raster(
    const float* __restrict__ faces,
    const float* __restrict__ textures,
    float* __restrict__ out, int B, int F)
{
    const int tid  = threadIdx.x;
    const int lane = tid & 63;
    const int w    = tid >> 6;         // 0..7
    const int q    = w & 3;            // quadrant within the 16x16 tile
    const int st   = w >> 2;           // stripe 0/1 of the face list
    const int b    = blockIdx.x >> 8;
    const int tile = blockIdx.x & 255;
    const int TX   = tile & 15;        // 16-px tile coords (0..15)
    const int TY   = tile >> 4;

    __shared__ float4 s_a[CAP_T];
    __shared__ float4 s_b[CAP_T];
    __shared__ float4 s_c[CAP_T];
    __shared__ int    s_i[CAP_T];      // face index
    __shared__ int    s_cnt;
    // Stripe-1 partials (stripe-0 keeps its own in registers):
    __shared__ float  s_pz[4][64];
    __shared__ int    s_pi[4][64];
    __shared__ float  s_pn[4][64][3];
    __shared__ float  s_pvz[4][64][3];

    if (tid == 0) s_cnt = 0;
    __syncthreads();

    // 16x16-tile pixel-center range (exact floats: small ints / 2^8) —
    // union of the 4 quadrant ranges used since R0.
    const float txlo = (float)(32 * TX +  1 - 256) * (1.0f / 256.0f);
    const float txhi = (float)(32 * TX + 31 - 256) * (1.0f / 256.0f);
    const float tylo = (float)(32 * TY +  1 - 256) * (1.0f / 256.0f);
    const float tyhi = (float)(32 * TY + 31 - 256) * (1.0f / 256.0f);

    // ---- phase A: local bin — scan all faces of image b -------------------
    // Escape bound: fp-inside region extends <= ~6e-8/|det| beyond the hull;
    // dilate 2e-3 + 3e-7/|det| (5x safety, <= 0.032). |det| < 1e-5 ->
    // unbounded escape -> always in the pool. Pool membership == the old
    // (quadmask != 0) test: overlap with the tile = union of quadrants.
    const float* fimg = faces + (size_t)b * F * 9;
    for (int f = tid; f < F; f += 512) {
        const float* fp = fimg + (size_t)f * 9;
        const float x0 = fp[0], y0 = fp[1], z0 = fp[2];
        const float x1 = fp[3], y1 = fp[4], z1 = fp[5];
        const float x2 = fp[6], y2 = fp[7], z2 = fp[8];

        const float det = (x1 - x0) * (y2 - y0) - (x2 - x0) * (y1 - y0);
        const float ad = fabsf(det);
        bool keep;
        if (ad < DET_GLOBAL) {
            keep = true;
        } else {
            const float d = 2e-3f + 3e-7f / ad;   // <= 0.032
            const float lox = fminf(x0, fminf(x1, x2)) - d;
            const float hix = fmaxf(x0, fmaxf(x1, x2)) + d;
            const float loy = fminf(y0, fminf(y1, y2)) - d;
            const float hiy = fmaxf(y0, fmaxf(y1, y2)) + d;
            // Dilation d (>= 2e-3 = 0.5 NDC px) dwarfs the ~1e-7 fp slack.
            keep = (hix >= txlo) && (lox <= txhi) && (hiy >= tylo) && (loy <= tyhi);
        }
        if (keep) {
            // Verified contracted numerics: C = fma(xa, yb, -(xb*ya)).
            const float A0 = subrn(x2, x1), B0 = subrn(y1, y2);
            const float C0 = fmarn(x1, y2, -mulrn(x2, y1));
            const float A1 = subrn(x0, x2), B1 = subrn(y2, y0);
            const float C1 = fmarn(x2, y0, -mulrn(x0, y2));
            const float A2 = subrn(x1, x0), B2 = subrn(y0, y1);
            const float C2 = fmarn(x0, y1, -mulrn(x1, y0));
            const int pos = atomicAdd(&s_cnt, 1);
            if (pos < CAP_T) {
                s_a[pos] = make_float4(A0, B0, C0, A1);
                s_b[pos] = make_float4(B1, C1, A2, B2);
                s_c[pos] = make_float4(C2, z0, z1, z2);
                s_i[pos] = f;
            }
        }
    }
    __syncthreads();
    const int cnt = min(s_cnt, CAP_T);

    // ---- phase B: wave (q, st) scans stripe st (entries st, st+2, ...) ----
    // Dense pipelined loop: no data-dependent branch; constants for entry
    // j+2 load (unconditionally) while entry j evaluates. Faces not
    // overlapping this wave's quadrant evaluate to ins=false (escape-bound
    // proof) — bit-identical to the old qbit-skip semantics.
    const int qtx = 2 * TX + (q & 1);
    const int qty = 2 * TY + (q >> 1);
    const int px  = qtx * 8 + (lane & 7);
    const int py  = qty * 8 + (lane >> 3);
    const float xp = (float)(2 * px + 1 - IS) * (1.0f / IS);  // exact (/2^8)
    const float yp = (float)(2 * py + 1 - IS) * (1.0f / IS);  // exact

    float bestz = FARP;
    int   besti = -1;
    float bn0 = 0.f, bn1 = 0.f, bn2 = 0.f;     // winner's normalized weights
    float bz0 = 1.f, bz1 = 1.f, bz2 = 1.f;     // winner's vertex depths

    float4 pa, pb, pc;
    int    pi = 0;
    if (st < cnt) {
        pa = s_a[st]; pb = s_b[st]; pc = s_c[st]; pi = s_i[st];
    }
    for (int j = st; j < cnt; j += 2) {
        const float4 fa  = pa;
        const float4 fb4 = pb;
        const float4 fc  = pc;
        const int    fi  = pi;
        const int jn = j + 2;
        if (jn < cnt) {   // prefetch next stripe entry (unconditional wrt data)
            pa = s_a[jn]; pb = s_b[jn]; pc = s_c[jn]; pi = s_i[jn];
        }
        // Contracted: w = fma(yp, A, xp*B) + C  (verified chain)
        const float w0 = addrn(fmarn(yp, fa.x, mulrn(xp, fa.y)), fa.z);
        const float w1 = addrn(fmarn(yp, fa.w, mulrn(xp, fb4.x)), fb4.y);
        const float w2 = addrn(fmarn(yp, fb4.z, mulrn(xp, fb4.w)), fc.x);
        const float det = addrn(addrn(w0, w1), w2);
        bool ins;
        if (det > TINYF)       ins = (w0 > 0.f) && (w1 > 0.f) && (w2 > 0.f);
        else if (det < -TINYF) ins = (w0 < 0.f) && (w1 < 0.f) && (w2 < 0.f);
        else                   ins = false;
        // Early-z: zp >= min(z) - ~5e-5 (absolute bound), so a face with
        // min(z) > bestz+ZEPS can neither win nor tie — exact per stripe.
        const float minz = fminf(fminf(fc.y, fc.z), fc.w);
        if (ins && minz <= bestz + ZEPS) {
            float n0 = divrn(w0, det), n1 = divrn(w1, det), n2 = divrn(w2, det);
            n0 = frn(fminf(fmaxf(n0, 0.f), 1.f));
            n1 = frn(fminf(fmaxf(n1, 0.f), 1.f));
            n2 = frn(fminf(fmaxf(n2, 0.f), 1.f));
            float s = addrn(addrn(n0, n1), n2);
            s = (s > TINYF) ? s : 1.0f;
            n0 = divrn(n0, s); n1 = divrn(n1, s); n2 = divrn(n2, s);
            float iz = addrn(addrn(divrn(n0, fc.y), divrn(n1, fc.z)),
                             divrn(n2, fc.w));
            iz = (fabsf(iz) > TINYF) ? iz : 1.0f;
            const float zp = divrn(1.0f, iz);
            if (zp > NEARP && zp < FARP) {
                if (zp < bestz || (zp == bestz && fi < besti)) {
                    bestz = zp;
                    besti = fi;
                    bn0 = n0; bn1 = n1; bn2 = n2;
                    bz0 = fc.y; bz1 = fc.z; bz2 = fc.w;
                }
            }
        }
    }

    // Stripe 1 publishes its partial; stripe 0 merges in registers.
    if (st == 1) {
        s_pz[q][lane] = bestz;
        s_pi[q][lane] = besti;
        s_pn[q][lane][0]  = bn0; s_pn[q][lane][1]  = bn1; s_pn[q][lane][2]  = bn2;
        s_pvz[q][lane][0] = bz0; s_pvz[q][lane][1] = bz1; s_pvz[q][lane][2] = bz2;
    }
    __syncthreads();

    // ---- phase C: stripe-0 waves merge + shade (R6/R9-verified merge:
    // lexicographic (z, smaller idx) = reference tie-break; empty partial is
    // (FARP,-1), real winners have z < FARP strictly). Shade from the winning
    // partial's saved state (R3-verified: bit-identical n*,z*,zp). ----------
    if (st == 0) {
        const float z1p = s_pz[q][lane];
        const int   i1p = s_pi[q][lane];
        if (z1p < bestz || (z1p == bestz && i1p < besti)) {
            bestz = z1p;
            besti = i1p;
            bn0 = s_pn[q][lane][0]; bn1 = s_pn[q][lane][1]; bn2 = s_pn[q][lane][2];
            bz0 = s_pvz[q][lane][0]; bz1 = s_pvz[q][lane][1]; bz2 = s_pvz[q][lane][2];
        }

        float r = 0.f, g = 0.f, bch = 0.f, alpha = 0.f, depth = FARP;
        if (besti >= 0) {
            const float zp = bestz;
            depth = zp;
            const float t0 = fminf(fmaxf(divrn(mulrn(mulrn(bn0, 3.0f), zp), bz0), 0.f), 2.999f);
            const float t1 = fminf(fmaxf(divrn(mulrn(mulrn(bn1, 3.0f), zp), bz1), 0.f), 2.999f);
            const float t2 = fminf(fmaxf(divrn(mulrn(mulrn(bn2, 3.0f), zp), bz2), 0.f), 2.999f);
            const float l0 = floorf(t0), l1 = floorf(t1), l2 = floorf(t2);
            const float fr0 = subrn(t0, l0), fr1 = subrn(t1, l1), fr2 = subrn(t2, l2);
            const int i0 = (int)l0, i1 = (int)l1, i2 = (int)l2;

            const float* txp = textures + (size_t)(b * F + besti) * 64 * 3;
            for (int d0 = 0; d0 < 2; ++d0)
                for (int d1 = 0; d1 < 2; ++d1)
                    for (int d2 = 0; d2 < 2; ++d2) {
                        const float wg = mulrn(mulrn(d0 ? fr0 : subrn(1.0f, fr0),
                                                     d1 ? fr1 : subrn(1.0f, fr1)),
                                               d2 ? fr2 : subrn(1.0f, fr2));
                        const float* tp = txp + ((i0 + d0) * 16 + (i1 + d1) * 4 + (i2 + d2)) * 3;
                        r   = addrn(r,   mulrn(wg, tp[0]));
                        g   = addrn(g,   mulrn(wg, tp[1]));
                        bch = addrn(bch, mulrn(wg, tp[2]));
                    }
            alpha = 1.0f;
        }

        float* op = out + (((size_t)b * IS + py) * IS + px) * 5;
        op[0] = r;
        op[1] = g;
        op[2] = bch;
        op[3] = alpha;
        op[4] = depth;
    }
}

extern "C" void kernel_launch(void* const* d_in, const int* in_sizes, int n_in,
                              void* d_out, int out_size, void* d_ws, size_t ws_size,
                              hipStream_t stream) {
    const float* faces    = (const float*)d_in[0];
    const float* textures = (const float*)d_in[1];
    float* out = (float*)d_out;
    const int F = FCOUNT;
    const int B = in_sizes[0] / (F * 9);

    fused_raster<<<dim3(B * 256), dim3(512), 0, stream>>>(
        faces, textures, out, B, F);
}

// Round 11
// 99.008 us; speedup vs baseline: 1.0074x; 1.0074x over previous
//
#include <hip/hip_runtime.h>

#define IS 256
#define FCOUNT 4096
#define NEARP 0.1f
#define FARP 100.0f
#define TINYF 1e-12f
#define CAP_T 320        // per-16x16-tile LDS list capacity (mean ~60-90; margin proven R2-R10)
#define DET_GLOBAL 1e-5f // |det| below this -> treat as covering all quadrants
#define ZEPS 2e-4f       // early-z slack: zp >= min(z)-5e-5 proven; 4x margin

// Value barrier: pins a value in a VGPR; no transform across it.
__device__ __forceinline__ float frn(float r) { asm("" : "+v"(r)); return r; }
__device__ __forceinline__ float mulrn(float a, float b) { return frn(a * b); }
__device__ __forceinline__ float addrn(float a, float b) { return frn(a + b); }
__device__ __forceinline__ float subrn(float a, float b) { return frn(a - b); }
__device__ __forceinline__ float divrn(float a, float b) { return frn(a / b); }
__device__ __forceinline__ float fmarn(float a, float b, float c) {
    return frn(__builtin_fmaf(a, b, c));
}

// ---------------------------------------------------------------------------
// R11 = synthesis of R9 (best, 94.65: qbit skip = low WORK) and R10
// (regression but informative: prefetch = low STALL, dropped skip = +13 us
// work). Decomposition from counters: R9 issue~18us stall~22us; R10 issue
// ~28us stall~17us. Here: keep R9's quadmask skip AND R10's register
// prefetch, ordered so the prefetch of entry j+2 issues BEFORE the skip test
// of entry j. The skip branch tests a value loaded two iterations ago ->
// no LDS-load->branch dependency; evals run from registers with the lgkm
// wait covered by a full iteration of independent work; skipped entries cost
// ~10 instrs. All accept-path numerics, stripe partition, partial-argmin +
// lexicographic (z, smaller idx) merge, and saved-state shade are the
// R9-verified structure op-for-op (bit-identical outputs).
// LDS: 16,644 (pool) + 8,192 (stripe-1 partials) ~= 24.8 KB -> 4 blocks/CU
// at 512 thr = 8 waves/SIMD.
// ---------------------------------------------------------------------------
__global__ __launch_bounds__(512, 8) void fused_raster(
    const float* __restrict__ faces,
    const float* __restrict__ textures,
    float* __restrict__ out, int B, int F)
{
    const int tid  = threadIdx.x;
    const int lane = tid & 63;
    const int w    = tid >> 6;         // 0..7
    const int q    = w & 3;            // quadrant within the 16x16 tile
    const int st   = w >> 2;           // stripe 0/1 of the face list
    const int b    = blockIdx.x >> 8;
    const int tile = blockIdx.x & 255;
    const int TX   = tile & 15;        // 16-px tile coords (0..15)
    const int TY   = tile >> 4;

    __shared__ float4 s_a[CAP_T];
    __shared__ float4 s_b[CAP_T];
    __shared__ float4 s_c[CAP_T];
    __shared__ int    s_i[CAP_T];      // f | (quadmask << 12)
    __shared__ int    s_cnt;
    // Stripe-1 partials (stripe-0 keeps its own in registers):
    __shared__ float  s_pz[4][64];
    __shared__ int    s_pi[4][64];
    __shared__ float  s_pn[4][64][3];
    __shared__ float  s_pvz[4][64][3];

    if (tid == 0) s_cnt = 0;
    __syncthreads();

    // Quadrant pixel-center ranges (exact floats: small ints / 2^8) —
    // identical to the original per-8x8-bin ranges (proven since R0).
    const float qxlo0 = (float)(32 * TX +  1 - 256) * (1.0f / 256.0f);
    const float qxhi0 = (float)(32 * TX + 15 - 256) * (1.0f / 256.0f);
    const float qxlo1 = (float)(32 * TX + 17 - 256) * (1.0f / 256.0f);
    const float qxhi1 = (float)(32 * TX + 31 - 256) * (1.0f / 256.0f);
    const float qylo0 = (float)(32 * TY +  1 - 256) * (1.0f / 256.0f);
    const float qyhi0 = (float)(32 * TY + 15 - 256) * (1.0f / 256.0f);
    const float qylo1 = (float)(32 * TY + 17 - 256) * (1.0f / 256.0f);
    const float qyhi1 = (float)(32 * TY + 31 - 256) * (1.0f / 256.0f);

    // ---- phase A: local bin — scan all faces of image b (R9-verified) -----
    // Escape bound: fp-inside region extends <= ~6e-8/|det| beyond the hull;
    // dilate 2e-3 + 3e-7/|det| (5x safety, <= 0.032). |det| < 1e-5 ->
    // unbounded escape -> conservatively cover all 4 quadrants.
    const float* fimg = faces + (size_t)b * F * 9;
    for (int f = tid; f < F; f += 512) {
        const float* fp = fimg + (size_t)f * 9;
        const float x0 = fp[0], y0 = fp[1], z0 = fp[2];
        const float x1 = fp[3], y1 = fp[4], z1 = fp[5];
        const float x2 = fp[6], y2 = fp[7], z2 = fp[8];

        const float det = (x1 - x0) * (y2 - y0) - (x2 - x0) * (y1 - y0);
        const float ad = fabsf(det);
        int mask;
        if (ad < DET_GLOBAL) {
            mask = 0xF;
        } else {
            const float d = 2e-3f + 3e-7f / ad;   // <= 0.032
            const float lox = fminf(x0, fminf(x1, x2)) - d;
            const float hix = fmaxf(x0, fmaxf(x1, x2)) + d;
            const float loy = fminf(y0, fminf(y1, y2)) - d;
            const float hiy = fmaxf(y0, fmaxf(y1, y2)) + d;
            // Dilation d (>= 2e-3 = 0.5 NDC px) dwarfs the ~1e-7 fp slack of
            // these compares (same argument as the ceil/floor bin bounds).
            const bool ox0 = (hix >= qxlo0) && (lox <= qxhi0);
            const bool ox1 = (hix >= qxlo1) && (lox <= qxhi1);
            const bool oy0 = (hiy >= qylo0) && (loy <= qyhi0);
            const bool oy1 = (hiy >= qylo1) && (loy <= qyhi1);
            mask = ((ox0 && oy0) ? 1 : 0) | ((ox1 && oy0) ? 2 : 0)
                 | ((ox0 && oy1) ? 4 : 0) | ((ox1 && oy1) ? 8 : 0);
        }
        if (mask) {
            // Verified contracted numerics: C = fma(xa, yb, -(xb*ya)).
            const float A0 = subrn(x2, x1), B0 = subrn(y1, y2);
            const float C0 = fmarn(x1, y2, -mulrn(x2, y1));
            const float A1 = subrn(x0, x2), B1 = subrn(y2, y0);
            const float C1 = fmarn(x2, y0, -mulrn(x0, y2));
            const float A2 = subrn(x1, x0), B2 = subrn(y0, y1);
            const float C2 = fmarn(x0, y1, -mulrn(x1, y0));
            const int pos = atomicAdd(&s_cnt, 1);
            if (pos < CAP_T) {
                s_a[pos] = make_float4(A0, B0, C0, A1);
                s_b[pos] = make_float4(B1, C1, A2, B2);
                s_c[pos] = make_float4(C2, z0, z1, z2);
                s_i[pos] = f | (mask << 12);
            }
        }
    }
    __syncthreads();
    const int cnt = min(s_cnt, CAP_T);

    // ---- phase B: wave (q, st) scans stripe st (entries st, st+2, ...) ----
    // Pipelined: entry j+2's {mask|idx, A, B, C} prefetch issues BEFORE the
    // skip test of entry j (which uses a value loaded two iterations ago) —
    // no LDS-load->branch dependency; evals consume registers only.
    const int qtx = 2 * TX + (q & 1);
    const int qty = 2 * TY + (q >> 1);
    const int px  = qtx * 8 + (lane & 7);
    const int py  = qty * 8 + (lane >> 3);
    const float xp = (float)(2 * px + 1 - IS) * (1.0f / IS);  // exact (/2^8)
    const float yp = (float)(2 * py + 1 - IS) * (1.0f / IS);  // exact
    const int qbit = 1 << (12 + q);

    float bestz = FARP;
    int   besti = -1;
    float bn0 = 0.f, bn1 = 0.f, bn2 = 0.f;     // winner's normalized weights
    float bz0 = 1.f, bz1 = 1.f, bz2 = 1.f;     // winner's vertex depths

    int    mi_c = 0;
    float4 a_c, b_c, c_c;
    if (st < cnt) {
        mi_c = s_i[st]; a_c = s_a[st]; b_c = s_b[st]; c_c = s_c[st];
    }
    for (int j = st; j < cnt; j += 2) {
        const int    mi  = mi_c;
        const float4 fa  = a_c;
        const float4 fb4 = b_c;
        const float4 fc  = c_c;
        const int jn = j + 2;
        if (jn < cnt) {   // prefetch next stripe entry before the skip test
            mi_c = s_i[jn]; a_c = s_a[jn]; b_c = s_b[jn]; c_c = s_c[jn];
        }
        if (!(mi & qbit)) continue;          // wave-uniform, register-only test
        // Contracted: w = fma(yp, A, xp*B) + C  (verified chain)
        const float w0 = addrn(fmarn(yp, fa.x, mulrn(xp, fa.y)), fa.z);
        const float w1 = addrn(fmarn(yp, fa.w, mulrn(xp, fb4.x)), fb4.y);
        const float w2 = addrn(fmarn(yp, fb4.z, mulrn(xp, fb4.w)), fc.x);
        const float det = addrn(addrn(w0, w1), w2);
        bool ins;
        if (det > TINYF)       ins = (w0 > 0.f) && (w1 > 0.f) && (w2 > 0.f);
        else if (det < -TINYF) ins = (w0 < 0.f) && (w1 < 0.f) && (w2 < 0.f);
        else                   ins = false;
        // Early-z: zp >= min(z) - ~5e-5 (absolute bound), so a face with
        // min(z) > bestz+ZEPS can neither win nor tie — exact per stripe.
        const float minz = fminf(fminf(fc.y, fc.z), fc.w);
        if (ins && minz <= bestz + ZEPS) {
            float n0 = divrn(w0, det), n1 = divrn(w1, det), n2 = divrn(w2, det);
            n0 = frn(fminf(fmaxf(n0, 0.f), 1.f));
            n1 = frn(fminf(fmaxf(n1, 0.f), 1.f));
            n2 = frn(fminf(fmaxf(n2, 0.f), 1.f));
            float s = addrn(addrn(n0, n1), n2);
            s = (s > TINYF) ? s : 1.0f;
            n0 = divrn(n0, s); n1 = divrn(n1, s); n2 = divrn(n2, s);
            float iz = addrn(addrn(divrn(n0, fc.y), divrn(n1, fc.z)),
                             divrn(n2, fc.w));
            iz = (fabsf(iz) > TINYF) ? iz : 1.0f;
            const float zp = divrn(1.0f, iz);
            if (zp > NEARP && zp < FARP) {
                const int fi = mi & 0xFFF;
                if (zp < bestz || (zp == bestz && fi < besti)) {
                    bestz = zp;
                    besti = fi;
                    bn0 = n0; bn1 = n1; bn2 = n2;
                    bz0 = fc.y; bz1 = fc.z; bz2 = fc.w;
                }
            }
        }
    }

    // Stripe 1 publishes its partial; stripe 0 merges in registers.
    if (st == 1) {
        s_pz[q][lane] = bestz;
        s_pi[q][lane] = besti;
        s_pn[q][lane][0]  = bn0; s_pn[q][lane][1]  = bn1; s_pn[q][lane][2]  = bn2;
        s_pvz[q][lane][0] = bz0; s_pvz[q][lane][1] = bz1; s_pvz[q][lane][2] = bz2;
    }
    __syncthreads();

    // ---- phase C: stripe-0 waves merge + shade (R6/R9-verified merge:
    // lexicographic (z, smaller idx) = reference tie-break; empty partial is
    // (FARP,-1), real winners have z < FARP strictly). Shade from the winning
    // partial's saved state (R3-verified: bit-identical n*,z*,zp). ----------
    if (st == 0) {
        const float z1p = s_pz[q][lane];
        const int   i1p = s_pi[q][lane];
        if (z1p < bestz || (z1p == bestz && i1p < besti)) {
            bestz = z1p;
            besti = i1p;
            bn0 = s_pn[q][lane][0]; bn1 = s_pn[q][lane][1]; bn2 = s_pn[q][lane][2];
            bz0 = s_pvz[q][lane][0]; bz1 = s_pvz[q][lane][1]; bz2 = s_pvz[q][lane][2];
        }

        float r = 0.f, g = 0.f, bch = 0.f, alpha = 0.f, depth = FARP;
        if (besti >= 0) {
            const float zp = bestz;
            depth = zp;
            const float t0 = fminf(fmaxf(divrn(mulrn(mulrn(bn0, 3.0f), zp), bz0), 0.f), 2.999f);
            const float t1 = fminf(fmaxf(divrn(mulrn(mulrn(bn1, 3.0f), zp), bz1), 0.f), 2.999f);
            const float t2 = fminf(fmaxf(divrn(mulrn(mulrn(bn2, 3.0f), zp), bz2), 0.f), 2.999f);
            const float l0 = floorf(t0), l1 = floorf(t1), l2 = floorf(t2);
            const float fr0 = subrn(t0, l0), fr1 = subrn(t1, l1), fr2 = subrn(t2, l2);
            const int i0 = (int)l0, i1 = (int)l1, i2 = (int)l2;

            const float* txp = textures + (size_t)(b * F + besti) * 64 * 3;
            for (int d0 = 0; d0 < 2; ++d0)
                for (int d1 = 0; d1 < 2; ++d1)
                    for (int d2 = 0; d2 < 2; ++d2) {
                        const float wg = mulrn(mulrn(d0 ? fr0 : subrn(1.0f, fr0),
                                                     d1 ? fr1 : subrn(1.0f, fr1)),
                                               d2 ? fr2 : subrn(1.0f, fr2));
                        const float* tp = txp + ((i0 + d0) * 16 + (i1 + d1) * 4 + (i2 + d2)) * 3;
                        r   = addrn(r,   mulrn(wg, tp[0]));
                        g   = addrn(g,   mulrn(wg, tp[1]));
                        bch = addrn(bch, mulrn(wg, tp[2]));
                    }
            alpha = 1.0f;
        }

        float* op = out + (((size_t)b * IS + py) * IS + px) * 5;
        op[0] = r;
        op[1] = g;
        op[2] = bch;
        op[3] = alpha;
        op[4] = depth;
    }
}

extern "C" void kernel_launch(void* const* d_in, const int* in_sizes, int n_in,
                              void* d_out, int out_size, void* d_ws, size_t ws_size,
                              hipStream_t stream) {
    const float* faces    = (const float*)d_in[0];
    const float* textures = (const float*)d_in[1];
    float* out = (float*)d_out;
    const int F = FCOUNT;
    const int B = in_sizes[0] / (F * 9);

    fused_raster<<<dim3(B * 256), dim3(512), 0, stream>>>(
        faces, textures, out, B, F);
}

// Round 12
// 94.831 us; speedup vs baseline: 1.0518x; 1.0440x over previous
//
#include <hip/hip_runtime.h>

#define IS 256
#define FCOUNT 4096
#define NEARP 0.1f
#define FARP 100.0f
#define TINYF 1e-12f
#define CAP_T 320        // per-16x16-tile LDS list capacity (mean ~60; >5x margin)
#define DET_GLOBAL 1e-5f // |det| below this -> treat as covering all quadrants
#define ZEPS 2e-4f       // early-z slack: zp >= min(z)-5e-5 proven; 4x margin

// Value barrier: pins a value in a VGPR; no transform across it.
__device__ __forceinline__ float frn(float r) { asm("" : "+v"(r)); return r; }
__device__ __forceinline__ float mulrn(float a, float b) { return frn(a * b); }
__device__ __forceinline__ float addrn(float a, float b) { return frn(a + b); }
__device__ __forceinline__ float subrn(float a, float b) { return frn(a - b); }
__device__ __forceinline__ float divrn(float a, float b) { return frn(a / b); }
__device__ __forceinline__ float fmarn(float a, float b, float c) {
    return frn(__builtin_fmaf(a, b, c));
}

// ---------------------------------------------------------------------------
// R12 = byte-exact revert to R9 (best measured: 94.65 us, passed).
// Session ledger: R2-R11 bracketed the kernel's work/stall trade-off —
// {R9 skip+no-prefetch: 40.3us} {R10 prefetch+no-skip: 45.4us}
// {R11 prefetch+skip: 43.0us} — flat minimum ~40us. All four bottleneck
// classes (instruction count R3/R4, load bandwidth R3, occupancy/TLP R9,
// latency chains R10/R11) individually exhausted. dur_us ≈ kernel + 54.3us
// fixed harness floor (42us 256MiB workspace poison fill at ~80% achievable
// HBM — itself roofline-bound — + ~12us graph-replay overhead), verified to
// ±0.5us across R8-R11. 94.65us is the empirical floor for this harness.
//
// Structure: fused single-dispatch; 512-thr blocks (8 waves/SIMD); wave =
// (quadrant q, stripe st); phase A local bin (scan all F faces, dilated-bbox
// quadmask, LDS pool); phase B striped mask-scan with early-z; partial
// argmin merged by lexicographic (z, smaller idx) = reference tie-break;
// phase C shade from saved state. All numeric chains frn-pinned, verified
// bit-identical across R0-R11 (absmax 0.0625 every round).
// ---------------------------------------------------------------------------
__global__ __launch_bounds__(512, 8) void fused_raster(
    const float* __restrict__ faces,
    const float* __restrict__ textures,
    float* __restrict__ out, int B, int F)
{
    const int tid  = threadIdx.x;
    const int lane = tid & 63;
    const int w    = tid >> 6;         // 0..7
    const int q    = w & 3;            // quadrant within the 16x16 tile
    const int st   = w >> 2;           // stripe 0/1 of the face list
    const int b    = blockIdx.x >> 8;
    const int tile = blockIdx.x & 255;
    const int TX   = tile & 15;        // 16-px tile coords (0..15)
    const int TY   = tile >> 4;

    __shared__ float4 s_a[CAP_T];
    __shared__ float4 s_b[CAP_T];
    __shared__ float4 s_c[CAP_T];
    __shared__ int    s_i[CAP_T];      // f | (quadmask << 12)
    __shared__ int    s_cnt;
    // Stripe-1 partials (stripe-0 keeps its own in registers):
    __shared__ float  s_pz[4][64];
    __shared__ int    s_pi[4][64];
    __shared__ float  s_pn[4][64][3];
    __shared__ float  s_pvz[4][64][3];

    if (tid == 0) s_cnt = 0;
    __syncthreads();

    // Quadrant pixel-center ranges (exact floats: small ints / 2^8) —
    // identical to the original per-8x8-bin ranges (proven since R0).
    const float qxlo0 = (float)(32 * TX +  1 - 256) * (1.0f / 256.0f);
    const float qxhi0 = (float)(32 * TX + 15 - 256) * (1.0f / 256.0f);
    const float qxlo1 = (float)(32 * TX + 17 - 256) * (1.0f / 256.0f);
    const float qxhi1 = (float)(32 * TX + 31 - 256) * (1.0f / 256.0f);
    const float qylo0 = (float)(32 * TY +  1 - 256) * (1.0f / 256.0f);
    const float qyhi0 = (float)(32 * TY + 15 - 256) * (1.0f / 256.0f);
    const float qylo1 = (float)(32 * TY + 17 - 256) * (1.0f / 256.0f);
    const float qyhi1 = (float)(32 * TY + 31 - 256) * (1.0f / 256.0f);

    // ---- phase A: local bin — scan all faces of image b (R2-verified) -----
    // Escape bound: fp-inside region extends <= ~6e-8/|det| beyond the hull;
    // dilate 2e-3 + 3e-7/|det| (5x safety, <= 0.032). |det| < 1e-5 ->
    // unbounded escape -> conservatively cover all 4 quadrants.
    const float* fimg = faces + (size_t)b * F * 9;
    for (int f = tid; f < F; f += 512) {
        const float* fp = fimg + (size_t)f * 9;
        const float x0 = fp[0], y0 = fp[1], z0 = fp[2];
        const float x1 = fp[3], y1 = fp[4], z1 = fp[5];
        const float x2 = fp[6], y2 = fp[7], z2 = fp[8];

        const float det = (x1 - x0) * (y2 - y0) - (x2 - x0) * (y1 - y0);
        const float ad = fabsf(det);
        int mask;
        if (ad < DET_GLOBAL) {
            mask = 0xF;
        } else {
            const float d = 2e-3f + 3e-7f / ad;   // <= 0.032
            const float lox = fminf(x0, fminf(x1, x2)) - d;
            const float hix = fmaxf(x0, fmaxf(x1, x2)) + d;
            const float loy = fminf(y0, fminf(y1, y2)) - d;
            const float hiy = fmaxf(y0, fmaxf(y1, y2)) + d;
            // Dilation d (>= 2e-3 = 0.5 NDC px) dwarfs the ~1e-7 fp slack of
            // these compares (same argument as the ceil/floor bin bounds).
            const bool ox0 = (hix >= qxlo0) && (lox <= qxhi0);
            const bool ox1 = (hix >= qxlo1) && (lox <= qxhi1);
            const bool oy0 = (hiy >= qylo0) && (loy <= qyhi0);
            const bool oy1 = (hiy >= qylo1) && (loy <= qyhi1);
            mask = ((ox0 && oy0) ? 1 : 0) | ((ox1 && oy0) ? 2 : 0)
                 | ((ox0 && oy1) ? 4 : 0) | ((ox1 && oy1) ? 8 : 0);
        }
        if (mask) {
            // Verified contracted numerics: C = fma(xa, yb, -(xb*ya)).
            const float A0 = subrn(x2, x1), B0 = subrn(y1, y2);
            const float C0 = fmarn(x1, y2, -mulrn(x2, y1));
            const float A1 = subrn(x0, x2), B1 = subrn(y2, y0);
            const float C1 = fmarn(x2, y0, -mulrn(x0, y2));
            const float A2 = subrn(x1, x0), B2 = subrn(y0, y1);
            const float C2 = fmarn(x0, y1, -mulrn(x1, y0));
            const int pos = atomicAdd(&s_cnt, 1);
            if (pos < CAP_T) {
                s_a[pos] = make_float4(A0, B0, C0, A1);
                s_b[pos] = make_float4(B1, C1, A2, B2);
                s_c[pos] = make_float4(C2, z0, z1, z2);
                s_i[pos] = f | (mask << 12);
            }
        }
    }
    __syncthreads();
    const int cnt = min(s_cnt, CAP_T);

    // ---- phase B: wave (q, st) scans stripe st of quadrant q's list -------
    const int qtx = 2 * TX + (q & 1);
    const int qty = 2 * TY + (q >> 1);
    const int px  = qtx * 8 + (lane & 7);
    const int py  = qty * 8 + (lane >> 3);
    const float xp = (float)(2 * px + 1 - IS) * (1.0f / IS);  // exact (/2^8)
    const float yp = (float)(2 * py + 1 - IS) * (1.0f / IS);  // exact
    const int qbit = 1 << (12 + q);

    float bestz = FARP;
    int   besti = -1;
    float bn0 = 0.f, bn1 = 0.f, bn2 = 0.f;     // winner's normalized weights
    float bz0 = 1.f, bz1 = 1.f, bz2 = 1.f;     // winner's vertex depths

    for (int j = st; j < cnt; j += 2) {
        const int mi = s_i[j];
        if (!(mi & qbit)) continue;          // wave-uniform skip
        const float4 fa  = s_a[j];
        const float4 fb4 = s_b[j];
        const float4 fc  = s_c[j];
        // Contracted: w = fma(yp, A, xp*B) + C  (verified chain)
        const float w0 = addrn(fmarn(yp, fa.x, mulrn(xp, fa.y)), fa.z);
        const float w1 = addrn(fmarn(yp, fa.w, mulrn(xp, fb4.x)), fb4.y);
        const float w2 = addrn(fmarn(yp, fb4.z, mulrn(xp, fb4.w)), fc.x);
        const float det = addrn(addrn(w0, w1), w2);
        bool ins;
        if (det > TINYF)       ins = (w0 > 0.f) && (w1 > 0.f) && (w2 > 0.f);
        else if (det < -TINYF) ins = (w0 < 0.f) && (w1 < 0.f) && (w2 < 0.f);
        else                   ins = false;
        // Early-z: zp >= min(z) - ~5e-5 (absolute bound), so a face with
        // min(z) > bestz+ZEPS can neither win nor tie — exact per stripe.
        const float minz = fminf(fminf(fc.y, fc.z), fc.w);
        if (ins && minz <= bestz + ZEPS) {
            float n0 = divrn(w0, det), n1 = divrn(w1, det), n2 = divrn(w2, det);
            n0 = frn(fminf(fmaxf(n0, 0.f), 1.f));
            n1 = frn(fminf(fmaxf(n1, 0.f), 1.f));
            n2 = frn(fminf(fmaxf(n2, 0.f), 1.f));
            float s = addrn(addrn(n0, n1), n2);
            s = (s > TINYF) ? s : 1.0f;
            n0 = divrn(n0, s); n1 = divrn(n1, s); n2 = divrn(n2, s);
            float iz = addrn(addrn(divrn(n0, fc.y), divrn(n1, fc.z)),
                             divrn(n2, fc.w));
            iz = (fabsf(iz) > TINYF) ? iz : 1.0f;
            const float zp = divrn(1.0f, iz);
            if (zp > NEARP && zp < FARP) {
                const int fi = mi & 0xFFF;
                if (zp < bestz || (zp == bestz && fi < besti)) {
                    bestz = zp;
                    besti = fi;
                    bn0 = n0; bn1 = n1; bn2 = n2;
                    bz0 = fc.y; bz1 = fc.z; bz2 = fc.w;
                }
            }
        }
    }

    // Stripe 1 publishes its partial; stripe 0 merges in registers.
    if (st == 1) {
        s_pz[q][lane] = bestz;
        s_pi[q][lane] = besti;
        s_pn[q][lane][0]  = bn0; s_pn[q][lane][1]  = bn1; s_pn[q][lane][2]  = bn2;
        s_pvz[q][lane][0] = bz0; s_pvz[q][lane][1] = bz1; s_pvz[q][lane][2] = bz2;
    }
    __syncthreads();

    // ---- phase C: stripe-0 waves merge + shade (R6-verified merge:
    // lexicographic (z, smaller idx) = reference tie-break; empty partial is
    // (FARP,-1) and any real winner has z < FARP strictly). Shade from the
    // winning partial's saved state (R3-verified: bit-identical n*,z*,zp). --
    if (st == 0) {
        const float z1p = s_pz[q][lane];
        const int   i1p = s_pi[q][lane];
        if (z1p < bestz || (z1p == bestz && i1p < besti)) {
            bestz = z1p;
            besti = i1p;
            bn0 = s_pn[q][lane][0]; bn1 = s_pn[q][lane][1]; bn2 = s_pn[q][lane][2];
            bz0 = s_pvz[q][lane][0]; bz1 = s_pvz[q][lane][1]; bz2 = s_pvz[q][lane][2];
        }

        float r = 0.f, g = 0.f, bch = 0.f, alpha = 0.f, depth = FARP;
        if (besti >= 0) {
            const float zp = bestz;
            depth = zp;
            const float t0 = fminf(fmaxf(divrn(mulrn(mulrn(bn0, 3.0f), zp), bz0), 0.f), 2.999f);
            const float t1 = fminf(fmaxf(divrn(mulrn(mulrn(bn1, 3.0f), zp), bz1), 0.f), 2.999f);
            const float t2 = fminf(fmaxf(divrn(mulrn(mulrn(bn2, 3.0f), zp), bz2), 0.f), 2.999f);
            const float l0 = floorf(t0), l1 = floorf(t1), l2 = floorf(t2);
            const float fr0 = subrn(t0, l0), fr1 = subrn(t1, l1), fr2 = subrn(t2, l2);
            const int i0 = (int)l0, i1 = (int)l1, i2 = (int)l2;

            const float* txp = textures + (size_t)(b * F + besti) * 64 * 3;
            for (int d0 = 0; d0 < 2; ++d0)
                for (int d1 = 0; d1 < 2; ++d1)
                    for (int d2 = 0; d2 < 2; ++d2) {
                        const float wg = mulrn(mulrn(d0 ? fr0 : subrn(1.0f, fr0),
                                                     d1 ? fr1 : subrn(1.0f, fr1)),
                                               d2 ? fr2 : subrn(1.0f, fr2));
                        const float* tp = txp + ((i0 + d0) * 16 + (i1 + d1) * 4 + (i2 + d2)) * 3;
                        r   = addrn(r,   mulrn(wg, tp[0]));
                        g   = addrn(g,   mulrn(wg, tp[1]));
                        bch = addrn(bch, mulrn(wg, tp[2]));
                    }
            alpha = 1.0f;
        }

        float* op = out + (((size_t)b * IS + py) * IS + px) * 5;
        op[0] = r;
        op[1] = g;
        op[2] = bch;
        op[3] = alpha;
        op[4] = depth;
    }
}

extern "C" void kernel_launch(void* const* d_in, const int* in_sizes, int n_in,
                              void* d_out, int out_size, void* d_ws, size_t ws_size,
                              hipStream_t stream) {
    const float* faces    = (const float*)d_in[0];
    const float* textures = (const float*)d_in[1];
    float* out = (float*)d_out;
    const int F = FCOUNT;
    const int B = in_sizes[0] / (F * 9);

    fused_raster<<<dim3(B * 256), dim3(512), 0, stream>>>(
        faces, textures, out, B, F);
}